// Round 8
// baseline (36.568 us; speedup 1.0000x reference)
//
#include <hip/hip_runtime.h>

// Problem constants (HierarchicalIntentClassifier: B=8192, D=768, E=8, K=32)
#define BB 8192
#define DD 768
#define EE 8
#define KK 32
#define BM 16              // rows per block
#define NBLK (BB / BM)     // 512 blocks = 2 per CU
#define NSTEP (DD / 32)    // 24 K-steps

typedef short    short8 __attribute__((ext_vector_type(8)));
typedef float    f32x4  __attribute__((ext_vector_type(4)));
typedef float    f32x8  __attribute__((ext_vector_type(8)));
typedef unsigned short us4 __attribute__((ext_vector_type(4)));

// RNE float -> bf16 bits (finite inputs; no NaN path needed)
__device__ __forceinline__ unsigned short f2bf(float f) {
  unsigned int u = __float_as_uint(f);
  u = (u + 0x7fffu + ((u >> 16) & 1u)) >> 16;
  return (unsigned short)u;
}

// ---------------------------------------------------------------------------
// Pack kernel: sub_W [E][D][K] fp32 -> Bp fragment-linear bf16.
// Thread t <-> fragment (e, s, half, lane), t = e*3072 + s*128 + half*64 + lane.
// Fragment = 8 shorts: sub_W[e][s*32 + (lane>>4)*8 + j][half*16 + (lane&15)],
// j = 0..7 — exactly the MFMA B-operand for output col k = half*16 + (lane&15)
// at K-step s. Write side is perfectly linear (one short8 per thread); in the
// consumer a wave's two per-step loads are each 1024 B wave-contiguous.
// (Unchanged from R7 — passed validation twice.)
// ---------------------------------------------------------------------------
__global__ __launch_bounds__(256) void pack_w(const float* __restrict__ sw,
                                              short* __restrict__ bp) {
  const int t    = blockIdx.x * 256 + threadIdx.x;   // 0 .. 24575
  const int lane = t & 63;
  const int half = (t >> 6) & 1;
  const int s    = (t >> 7) % NSTEP;
  const int e    = (t >> 7) / NSTEP;
  const int lc   = lane & 15, hi = lane >> 4;
  const int k    = half * 16 + lc;
  const int d0   = s * 32 + hi * 8;
  const float* src = sw + ((size_t)(e * DD + d0)) * KK + k;
  short8 v;
#pragma unroll
  for (int j = 0; j < 8; ++j) v[j] = (short)f2bf(src[(size_t)j * KK]);
  *(short8*)(bp + (size_t)t * 8) = v;
}

// ---------------------------------------------------------------------------
// Fused kernel: 512 threads (8 waves), BM=16 rows/block, 512 blocks (2/CU).
// Phase 1 (R8 change): ALL 6 pooled loads (the slow L3/HBM stream) issued
//   up-front into av[3][2] — collapses 3 serial latency rounds (R7's
//   unroll-1) into 1. LDS stashes issued immediately after the loads.
//   main_W loads stay per-iteration (24 KB, L1-hot, cheap).
//   VGPR est ~90-110 < 128 => keeps 2 blocks/CU.
// Phase 2: wave w = expert w; per K-step: 2 wave-contiguous 1 KB global
//   B-loads (fragment-linear Bp) + 1 A ds_read + 2 MFMA, unroll 4.
//   (Byte-identical to R7.)
// Exactly ONE __syncthreads in the kernel.
// ---------------------------------------------------------------------------
__global__ __launch_bounds__(512) void fused(
    const float* __restrict__ pooled, const float* __restrict__ mW,
    const float* __restrict__ mb, const short* __restrict__ Bp,
    const float* __restrict__ sub_b, const int* __restrict__ sub_sizes,
    float* __restrict__ main_out, float* __restrict__ sub_out) {
  // 776 = 768 + 8 shorts pad (row stride 1552 B): avoids power-of-2
  // column->bank aliasing on the phase-2 ds_read_b128s.
  __shared__ short aS[BM][776];
  __shared__ int   idxS[BM];
  __shared__ int   szS[BM];

  const int t    = threadIdx.x;
  const int w    = t >> 6;
  const int lane = t & 63;
  const int row0 = blockIdx.x * BM;

  // ---- Phase 1: main GEMV (fp32) + bf16 stash, 2 rows per wave ----
  // Step A: issue all pooled loads (slow stream) + stash to LDS.
  f32x4 av[3][2];
#pragma unroll
  for (int i = 0; i < 3; ++i) {
    const int d = (i * 64 + lane) * 4;
#pragma unroll
    for (int rr = 0; rr < 2; ++rr) {
      const int r = w * 2 + rr;
      av[i][rr] = *(const f32x4*)(pooled + (size_t)(row0 + r) * DD + d);
    }
  }
#pragma unroll
  for (int i = 0; i < 3; ++i) {
    const int d = (i * 64 + lane) * 4;
#pragma unroll
    for (int rr = 0; rr < 2; ++rr) {
      const int r = w * 2 + rr;
      f32x4 v = av[i][rr];
      us4 u;
      u[0] = f2bf(v[0]); u[1] = f2bf(v[1]); u[2] = f2bf(v[2]); u[3] = f2bf(v[3]);
      *(us4*)&aS[r][d] = u;
    }
  }
  // Step B: per-iteration W loads (L1-hot) + FMAs.
  f32x8 acc[2] = {};
#pragma unroll
  for (int i = 0; i < 3; ++i) {
    const int d = (i * 64 + lane) * 4;
    f32x8 W0 = *(const f32x8*)(mW + (size_t)(d + 0) * EE);
    f32x8 W1 = *(const f32x8*)(mW + (size_t)(d + 1) * EE);
    f32x8 W2 = *(const f32x8*)(mW + (size_t)(d + 2) * EE);
    f32x8 W3 = *(const f32x8*)(mW + (size_t)(d + 3) * EE);
#pragma unroll
    for (int rr = 0; rr < 2; ++rr) {
      acc[rr] += av[i][rr][0] * W0;
      acc[rr] += av[i][rr][1] * W1;
      acc[rr] += av[i][rr][2] * W2;
      acc[rr] += av[i][rr][3] * W3;
    }
  }
#pragma unroll
  for (int rr = 0; rr < 2; ++rr) {
#pragma unroll
    for (int off = 32; off >= 1; off >>= 1) {
#pragma unroll
      for (int j = 0; j < 8; ++j) acc[rr][j] += __shfl_xor(acc[rr][j], off);
    }
    if (lane == 0) {
      const int r = w * 2 + rr;
      f32x8 res = acc[rr] + *(const f32x8*)mb;
      *(f32x8*)(main_out + (size_t)(row0 + r) * EE) = res;
      float best = res[0];
      int   bi   = 0;
#pragma unroll
      for (int e = 1; e < EE; ++e) {
        if (res[e] > best) { best = res[e]; bi = e; }
      }
      idxS[r] = bi;
      szS[r]  = sub_sizes[bi];
    }
  }
  __syncthreads();

  // ---- Phase 2: MFMA. Wave w = expert w; fragment-linear coalesced B. ----
  const int lc = lane & 15, hi = lane >> 4;
  // Per expert: NSTEP steps x 2 halves x 64 lanes x 8 shorts = 24576 shorts.
  const short* bpw = Bp + (size_t)w * (NSTEP * 1024) + (size_t)lane * 8;
  f32x4 c0 = {0.f, 0.f, 0.f, 0.f}, c1 = {0.f, 0.f, 0.f, 0.f};

#pragma unroll 4
  for (int s = 0; s < NSTEP; ++s) {
    short8 b0 = *(const short8*)(bpw + s * 1024);        // half 0: k = lc
    short8 b1 = *(const short8*)(bpw + s * 1024 + 512);  // half 1: k = 16+lc
    short8 a0 = *(const short8*)&aS[lc][s * 32 + hi * 8];
    c0 = __builtin_amdgcn_mfma_f32_16x16x32_bf16(a0, b0, c0, 0, 0, 0);
    c1 = __builtin_amdgcn_mfma_f32_16x16x32_bf16(a0, b1, c1, 0, 0, 0);
  }

  // ---- Epilogue: routed select + bias + size mask; each (row,k) once ----
#pragma unroll
  for (int n = 0; n < 2; ++n) {
    const int k = n * 16 + lc;
    const float bias = sub_b[w * KK + k];
    const f32x4 cc = n ? c1 : c0;
#pragma unroll
    for (int q = 0; q < 4; ++q) {
      const int rl = hi * 4 + q;           // C/D: col=lane&15, row=(l>>4)*4+q
      if (idxS[rl] == w) {
        float v = cc[q] + bias;
        if (k >= szS[rl]) v = 0.f;
        sub_out[(size_t)(row0 + rl) * KK + k] = v;
      }
    }
  }
}

// ---------------------------------------------------------------------------
extern "C" void kernel_launch(void* const* d_in, const int* in_sizes, int n_in,
                              void* d_out, int out_size, void* d_ws, size_t ws_size,
                              hipStream_t stream) {
  const float* pooled   = (const float*)d_in[0];
  const float* main_W   = (const float*)d_in[1];
  const float* main_b   = (const float*)d_in[2];
  const float* sub_W    = (const float*)d_in[3];
  const float* sub_b    = (const float*)d_in[4];
  const int*   sub_size = (const int*)d_in[5];

  float* main_out = (float*)d_out;                    // [B, E]
  float* sub_out  = (float*)d_out + (size_t)BB * EE;  // [B, K]
  short* Bp       = (short*)d_ws;                     // fragment-linear, 384 KB

  pack_w<<<96, 256, 0, stream>>>(sub_W, Bp);
  fused<<<NBLK, 512, 0, stream>>>(pooled, main_W, main_b, Bp, sub_b,
                                  sub_size, main_out, sub_out);
}

// Round 9
// 29.649 us; speedup vs baseline: 1.2334x; 1.2334x over previous
//
#include <hip/hip_runtime.h>

// Problem constants (HierarchicalIntentClassifier: B=8192, D=768, E=8, K=32)
#define BB 8192
#define DD 768
#define EE 8
#define KK 32
#define BM 32              // rows per block (R9: 32, halves packed-B L2 traffic)
#define NBLK (BB / BM)     // 256 blocks
#define NSTEP (DD / 32)    // 24 K-steps

typedef short    short8 __attribute__((ext_vector_type(8)));
typedef float    f32x4  __attribute__((ext_vector_type(4)));
typedef float    f32x8  __attribute__((ext_vector_type(8)));
typedef unsigned short us4 __attribute__((ext_vector_type(4)));

// RNE float -> bf16 bits (finite inputs; no NaN path needed)
__device__ __forceinline__ unsigned short f2bf(float f) {
  unsigned int u = __float_as_uint(f);
  u = (u + 0x7fffu + ((u >> 16) & 1u)) >> 16;
  return (unsigned short)u;
}

// ---------------------------------------------------------------------------
// Pack kernel (unchanged from R7 — passed twice): sub_W [E][D][K] fp32 ->
// Bp fragment-linear bf16. t = e*3072 + s*128 + half*64 + lane; fragment =
// sub_W[e][s*32 + (lane>>4)*8 + j][half*16 + (lane&15)], j=0..7 — the MFMA
// B-operand for output col k = half*16+(lane&15) at K-step s. Consumer loads
// are 1024 B wave-contiguous.
// ---------------------------------------------------------------------------
__global__ __launch_bounds__(256) void pack_w(const float* __restrict__ sw,
                                              short* __restrict__ bp) {
  const int t    = blockIdx.x * 256 + threadIdx.x;   // 0 .. 24575
  const int lane = t & 63;
  const int half = (t >> 6) & 1;
  const int s    = (t >> 7) % NSTEP;
  const int e    = (t >> 7) / NSTEP;
  const int lc   = lane & 15, hi = lane >> 4;
  const int k    = half * 16 + lc;
  const int d0   = s * 32 + hi * 8;
  const float* src = sw + ((size_t)(e * DD + d0)) * KK + k;
  short8 v;
#pragma unroll
  for (int j = 0; j < 8; ++j) v[j] = (short)f2bf(src[(size_t)j * KK]);
  *(short8*)(bp + (size_t)t * 8) = v;
}

// ---------------------------------------------------------------------------
// Fused kernel: 512 threads (8 waves), BM=32 rows/block, 256 blocks.
// Phase 1: R1/R2-proven shape — wave w computes fp32 main logits for rows
//          {4w..4w+3} (exact argmax source), stashing pooled as bf16 into
//          LDS along the way; unroll 1, per-iteration W loads (L1-hot).
// Phase 2: wave w = expert w; TWO 16-row M-tiles per wave. Per K-step:
//          2 wave-contiguous 1 KB B-loads + 2 A ds_reads + 4 MFMA, unroll 4.
//          Packed-B L2 traffic: 256 blk x 384 KB = 100 MB (half of R7).
// Exactly ONE __syncthreads in the kernel. No min-waves hint.
// ---------------------------------------------------------------------------
__global__ __launch_bounds__(512) void fused(
    const float* __restrict__ pooled, const float* __restrict__ mW,
    const float* __restrict__ mb, const short* __restrict__ Bp,
    const float* __restrict__ sub_b, const int* __restrict__ sub_sizes,
    float* __restrict__ main_out, float* __restrict__ sub_out) {
  // 776 = 768 + 8 shorts pad (row stride 1552 B): avoids power-of-2
  // column->bank aliasing on the phase-2 ds_read_b128s.
  __shared__ short aS[BM][776];
  __shared__ int   idxS[BM];
  __shared__ int   szS[BM];

  const int t    = threadIdx.x;
  const int w    = t >> 6;
  const int lane = t & 63;
  const int row0 = blockIdx.x * BM;

  // ---- Phase 1: main GEMV (fp32) + bf16 stash, 4 rows per wave ----
  f32x8 acc[4] = {};
#pragma unroll 1
  for (int i = 0; i < 3; ++i) {
    const int d = (i * 64 + lane) * 4;
    f32x8 W0 = *(const f32x8*)(mW + (size_t)(d + 0) * EE);
    f32x8 W1 = *(const f32x8*)(mW + (size_t)(d + 1) * EE);
    f32x8 W2 = *(const f32x8*)(mW + (size_t)(d + 2) * EE);
    f32x8 W3 = *(const f32x8*)(mW + (size_t)(d + 3) * EE);
#pragma unroll
    for (int rr = 0; rr < 4; ++rr) {
      const int r = w * 4 + rr;
      f32x4 v = *(const f32x4*)(pooled + (size_t)(row0 + r) * DD + d);
      us4 u;
      u[0] = f2bf(v[0]); u[1] = f2bf(v[1]); u[2] = f2bf(v[2]); u[3] = f2bf(v[3]);
      *(us4*)&aS[r][d] = u;
      acc[rr] += v[0] * W0;
      acc[rr] += v[1] * W1;
      acc[rr] += v[2] * W2;
      acc[rr] += v[3] * W3;
    }
  }
#pragma unroll
  for (int rr = 0; rr < 4; ++rr) {
#pragma unroll
    for (int off = 32; off >= 1; off >>= 1) {
#pragma unroll
      for (int j = 0; j < 8; ++j) acc[rr][j] += __shfl_xor(acc[rr][j], off);
    }
    if (lane == 0) {
      const int r = w * 4 + rr;
      f32x8 res = acc[rr] + *(const f32x8*)mb;
      *(f32x8*)(main_out + (size_t)(row0 + r) * EE) = res;
      float best = res[0];
      int   bi   = 0;
#pragma unroll
      for (int e = 1; e < EE; ++e) {
        if (res[e] > best) { best = res[e]; bi = e; }
      }
      idxS[r] = bi;
      szS[r]  = sub_sizes[bi];
    }
  }
  __syncthreads();

  // ---- Phase 2: MFMA. Wave w = expert w; two M-tiles; coalesced B. ----
  const int lc = lane & 15, hi = lane >> 4;
  // Per expert: NSTEP steps x 2 halves x 64 lanes x 8 shorts = 24576 shorts.
  const short* bpw = Bp + (size_t)w * (NSTEP * 1024) + (size_t)lane * 8;
  f32x4 c[2][2] = {};   // [mtile][khalf], all indices compile-time in unrolls

#pragma unroll 4
  for (int s = 0; s < NSTEP; ++s) {
    short8 b0 = *(const short8*)(bpw + s * 1024);        // half 0: k = lc
    short8 b1 = *(const short8*)(bpw + s * 1024 + 512);  // half 1: k = 16+lc
    const int dd = s * 32 + hi * 8;
    short8 a0 = *(const short8*)&aS[lc][dd];             // rows 0-15
    short8 a1 = *(const short8*)&aS[16 + lc][dd];        // rows 16-31
    c[0][0] = __builtin_amdgcn_mfma_f32_16x16x32_bf16(a0, b0, c[0][0], 0, 0, 0);
    c[0][1] = __builtin_amdgcn_mfma_f32_16x16x32_bf16(a0, b1, c[0][1], 0, 0, 0);
    c[1][0] = __builtin_amdgcn_mfma_f32_16x16x32_bf16(a1, b0, c[1][0], 0, 0, 0);
    c[1][1] = __builtin_amdgcn_mfma_f32_16x16x32_bf16(a1, b1, c[1][1], 0, 0, 0);
  }

  // ---- Epilogue: routed select + bias + size mask; each (row,k) once ----
#pragma unroll
  for (int n = 0; n < 2; ++n) {
    const int k = n * 16 + lc;
    const float bias = sub_b[w * KK + k];
#pragma unroll
    for (int mt = 0; mt < 2; ++mt) {
#pragma unroll
      for (int q = 0; q < 4; ++q) {
        const int rl = mt * 16 + hi * 4 + q;  // C/D: col=lane&15, row=(l>>4)*4+q
        if (idxS[rl] == w) {
          float v = c[mt][n][q] + bias;
          if (k >= szS[rl]) v = 0.f;
          sub_out[(size_t)(row0 + rl) * KK + k] = v;
        }
      }
    }
  }
}

// ---------------------------------------------------------------------------
extern "C" void kernel_launch(void* const* d_in, const int* in_sizes, int n_in,
                              void* d_out, int out_size, void* d_ws, size_t ws_size,
                              hipStream_t stream) {
  const float* pooled   = (const float*)d_in[0];
  const float* main_W   = (const float*)d_in[1];
  const float* main_b   = (const float*)d_in[2];
  const float* sub_W    = (const float*)d_in[3];
  const float* sub_b    = (const float*)d_in[4];
  const int*   sub_size = (const int*)d_in[5];

  float* main_out = (float*)d_out;                    // [B, E]
  float* sub_out  = (float*)d_out + (size_t)BB * EE;  // [B, K]
  short* Bp       = (short*)d_ws;                     // fragment-linear, 384 KB

  pack_w<<<96, 256, 0, stream>>>(sub_W, Bp);
  fused<<<NBLK, 512, 0, stream>>>(pooled, main_W, main_b, Bp, sub_b,
                                  sub_size, main_out, sub_out);
}